// Round 21
// baseline (791.820 us; speedup 1.0000x reference)
//
#include <hip/hip_runtime.h>
#include <hip/hip_bf16.h>

#define Nn 16384
#define Dd 256
#define L2E 1.4426950408889634f
#define LN2 0.6931471805599453f

typedef __attribute__((ext_vector_type(8))) int int8v;
typedef __attribute__((ext_vector_type(16))) float f32x16;
typedef __attribute__((ext_vector_type(2))) float f32x2;

__device__ inline void gload_lds16(const void* g, void* l) {
    __builtin_amdgcn_global_load_lds(
        (const __attribute__((address_space(1))) void*)g,
        (__attribute__((address_space(3))) void*)l, 16, 0, 0);
}

// fp32 -> fp8 e4m3 (HW RNE). A pre-scaled by log2e: epilogue softplus works in
// exp2/log2 domain with no per-element muls.
__global__ __launch_bounds__(256) void cvt_kernel(
        const float4* __restrict__ a, const float4* __restrict__ b,
        int2* __restrict__ oa, int2* __restrict__ ob) {
    int i = blockIdx.x * 256 + threadIdx.x;
    float4 a0 = a[2 * i], a1 = a[2 * i + 1];
    float4 b0 = b[2 * i], b1 = b[2 * i + 1];
    int alo = __builtin_amdgcn_cvt_pk_fp8_f32(a0.x * L2E, a0.y * L2E, 0, false);
    alo     = __builtin_amdgcn_cvt_pk_fp8_f32(a0.z * L2E, a0.w * L2E, alo, true);
    int ahi = __builtin_amdgcn_cvt_pk_fp8_f32(a1.x * L2E, a1.y * L2E, 0, false);
    ahi     = __builtin_amdgcn_cvt_pk_fp8_f32(a1.z * L2E, a1.w * L2E, ahi, true);
    int blo = __builtin_amdgcn_cvt_pk_fp8_f32(b0.x, b0.y, 0, false);
    blo     = __builtin_amdgcn_cvt_pk_fp8_f32(b0.z, b0.w, blo, true);
    int bhi = __builtin_amdgcn_cvt_pk_fp8_f32(b1.x, b1.y, 0, false);
    bhi     = __builtin_amdgcn_cvt_pk_fp8_f32(b1.z, b1.w, bhi, true);
    oa[i] = make_int2(alo, ahi);
    ob[i] = make_int2(blo, bhi);
}

// 2x ds_read_b128 of one lane's 32 contiguous K-bytes from a [rows][256B]
// full-K LDS tile, XOR-deswizzled (16 chunks/row, chunk ^= row&15).
// Measured ZERO bank conflicts (R8-R20). LDS dest LINEAR (rule #21);
// swizzle lives on the global SOURCE side only.
__device__ inline int8v read_frag256(const unsigned char* base, int rr, int cb) {
    int x = rr & 15;
    int4 lo = *(const int4*)&base[rr * 256 + ((cb ^ x) * 16)];
    int4 hi = *(const int4*)&base[rr * 256 + (((cb + 1) ^ x) * 16)];
    int8v r;
    r[0] = lo.x; r[1] = lo.y; r[2] = lo.z; r[3] = lo.w;
    r[4] = hi.x; r[5] = hi.y; r[6] = hi.z; r[7] = hi.w;
    return r;
}

#define MFMA_(A, B, C) __builtin_amdgcn_mfma_scale_f32_32x32x64_f8f6f4(       \
    (A), (B), (C), 0, 0, 0, 0x7F7F7F7F, 0, 0x7F7F7F7F)

// Fused MX-fp8 GEMM (sim' = log2e * za.zb^T, unit e8m0 scales) + siglip loss.
// R21: persistent-A pipelined-B (R18 base, 256 thr = 1 wave/SIMD) with TWO
// HALF-SIZE acc generations (accA/accB = acc[2][2] each, 64+64 = 128 AGPR —
// exactly R18's proven AGPR load; R19's spill was 2x[2][4] = 256 AGPR).
// 16 panels of 64 cols; PANEL_COMPUTE(cur) and PANEL_EPILOGUE(prev) share
// one barrier-free scheduler region -> epilogue VALU/trans interleaves into
// the MFMA pipe's idle slots (in R18/R20 the RDBAR fenced them apart, so
// phases added serially — that was the last 42%-VALUBusy/22%-MfmaUtil wall).
__global__ __launch_bounds__(256, 1) void siglip_kernel(
        const unsigned char* __restrict__ ga,   // za*log2e fp8 [16384][256]
        const unsigned char* __restrict__ gb,   // zb fp8 [16384][256]
        const float* __restrict__ bp,           // bias scalar
        float* __restrict__ out) {
    __shared__ unsigned char As[256 * 256];   // 64 KB, full-K A tile
    __shared__ unsigned char Bs0[64 * 256];   // 16 KB, B panel buffer 0
    __shared__ unsigned char Bs1[64 * 256];   // 16 KB, B panel buffer 1
    __shared__ float wsum[4];

    const int tid  = threadIdx.x;
    const int lane = tid & 63;
    const int wid  = tid >> 6;     // 0..3
    const int wm   = wid;          // 64-row slice of the 256-row tile
    const int l31  = lane & 31;
    const int h    = lane >> 5;

    // XCD-chunked bijective swizzle (grid 1024 = 8 XCD x 128); consecutive
    // nid share the A panel (same by) and sweep B -> per-XCD L2 locality.
    const int bid = blockIdx.x;
    const int nid = (bid & 7) * 128 + (bid >> 3);
    const int by  = nid >> 4;      // 0..63  M-tile (256 rows)
    const int bxs = nid & 15;      // 0..15  N-supertile (1024 cols)
    const size_t rowA0 = (size_t)by * 256;
    const int    rB0   = bxs * 1024;

    const float b2   = bp[0] * L2E;
    const int diagblk = (bxs == (by >> 2));
    const int dby3    = by & 3;

    // ---- stage A once: 16 loads/thread; LDS dest linear, source swizzled ----
#pragma unroll
    for (int p = 0; p < 16; ++p) {
        int c = p * 256 + tid; int row = c >> 4;
        int scl = (c & 15) ^ (row & 15);
        gload_lds16(&ga[(rowA0 + row) * Dd + scl * 16], &As[c * 16]);
    }

    // B panel = 64 rows x 256B = 1024 chunks -> 4 loads/thread.
#define STAGE_B(DST, T)                                                       \
    {                                                                         \
        _Pragma("unroll")                                                     \
        for (int p = 0; p < 4; ++p) {                                         \
            int c = p * 256 + tid; int row = c >> 4;                          \
            int scl = (c & 15) ^ (row & 15);                                  \
            gload_lds16(&gb[(size_t)(rB0 + (T) * 64 + row) * Dd + scl * 16],  \
                        &(DST)[c * 16]);                                      \
        }                                                                     \
    }

    STAGE_B(Bs0, 0)
    STAGE_B(Bs1, 1)

    f32x2 sm = {0.f, 0.f}, se = {0.f, 0.f};
    float ld = 0.f;

    f32x16 accA[2][2], accB[2][2];

    // init + 4 s-steps x {4 ds_reads, 4 MFMAs}; wave tile 64(M) x 64(N)
#define PANEL_COMPUTE(ACC, BBUF)                                              \
    {                                                                         \
        _Pragma("unroll")                                                     \
        for (int mf = 0; mf < 2; ++mf)                                        \
            _Pragma("unroll")                                                 \
            for (int nf = 0; nf < 2; ++nf)                                    \
                _Pragma("unroll")                                             \
                for (int q = 0; q < 16; ++q) (ACC)[mf][nf][q] = -b2;          \
        _Pragma("unroll")                                                     \
        for (int s = 0; s < 4; ++s) {                                         \
            int cb = s * 4 + h * 2;                                           \
            int8v aF0 = read_frag256(As, wm * 64 + l31, cb);                  \
            int8v aF1 = read_frag256(As, wm * 64 + 32 + l31, cb);             \
            int8v bF0 = read_frag256(BBUF, l31, cb);                          \
            int8v bF1 = read_frag256(BBUF, 32 + l31, cb);                     \
            (ACC)[0][0] = MFMA_(aF0, bF0, (ACC)[0][0]);                       \
            (ACC)[0][1] = MFMA_(aF0, bF1, (ACC)[0][1]);                       \
            (ACC)[1][0] = MFMA_(aF1, bF0, (ACC)[1][0]);                       \
            (ACC)[1][1] = MFMA_(aF1, bF1, (ACC)[1][1]);                       \
        }                                                                     \
    }

    // loss/elem(nats) ~= ln2*m + 2^(y-2m), m=max(y,0) [y-2m == -|y|].
    // Diagonal panels: T in [dby3*4, dby3*4+4), hit wave wm==(T&3); within,
    // only mf==nf frags, at rq==l31 (derivation: global row==col collapses).
#define PANEL_EPILOGUE(ACC, TT)                                               \
    {                                                                         \
        _Pragma("unroll")                                                     \
        for (int mf = 0; mf < 2; ++mf)                                        \
            _Pragma("unroll")                                                 \
            for (int nf = 0; nf < 2; ++nf)                                    \
                _Pragma("unroll")                                             \
                for (int q = 0; q < 16; q += 2) {                             \
                    f32x2 yv = {(ACC)[mf][nf][q], (ACC)[mf][nf][q + 1]};      \
                    f32x2 mv = {fmaxf(yv[0], 0.f), fmaxf(yv[1], 0.f)};        \
                    f32x2 tv = yv - 2.f * mv;                                 \
                    sm += mv;                                                 \
                    f32x2 ev = {__builtin_amdgcn_exp2f(tv[0]),                \
                                __builtin_amdgcn_exp2f(tv[1])};               \
                    se += ev;                                                 \
                }                                                             \
        if (diagblk && ((TT) >> 2) == dby3 && wm == ((TT) & 3)) {             \
            _Pragma("unroll")                                                 \
            for (int mf = 0; mf < 2; ++mf)                                    \
                _Pragma("unroll")                                             \
                for (int q = 0; q < 16; ++q) {                                \
                    int rq = (q & 3) + 8 * (q >> 2) + 4 * h;                  \
                    if (rq == l31) {                                          \
                        float y  = (ACC)[mf][mf][q];                          \
                        float u  = -(y + 2.f * b2);                           \
                        float ey = __builtin_amdgcn_exp2f(-fabsf(y));         \
                        float eu = __builtin_amdgcn_exp2f(-fabsf(u));         \
                        ld += (LN2 * fmaxf(u, 0.f) + eu) -                    \
                              (LN2 * fmaxf(y, 0.f) + ey);                     \
                    }                                                         \
                }                                                             \
        }                                                                     \
    }

#define RDBAR  asm volatile("" ::: "memory"); __builtin_amdgcn_s_barrier();   \
               asm volatile("" ::: "memory");
#define WAIT4  asm volatile("s_waitcnt vmcnt(4)" ::: "memory");               \
               __builtin_amdgcn_s_barrier(); asm volatile("" ::: "memory");
#define WAIT0  asm volatile("s_waitcnt vmcnt(0)" ::: "memory");               \
               __builtin_amdgcn_s_barrier(); asm volatile("" ::: "memory");

    // outstanding: A(16)+B0(4)+B1(4)=24; wait to <=4 -> A and B0 landed.
    WAIT4

    // ---- 16 panels; epilogue(T-1) fused into panel T's compute REGION
    // (no barrier between them -> scheduler interleaves VALU into MFMA gaps).
    PANEL_COMPUTE(accA, Bs0)                                   // T=0
    RDBAR  STAGE_B(Bs0, 2)   WAIT4
    PANEL_COMPUTE(accB, Bs1)  PANEL_EPILOGUE(accA, 0)          // T=1
    RDBAR  STAGE_B(Bs1, 3)   WAIT4
    PANEL_COMPUTE(accA, Bs0)  PANEL_EPILOGUE(accB, 1)          // T=2
    RDBAR  STAGE_B(Bs0, 4)   WAIT4
    PANEL_COMPUTE(accB, Bs1)  PANEL_EPILOGUE(accA, 2)          // T=3
    RDBAR  STAGE_B(Bs1, 5)   WAIT4
    PANEL_COMPUTE(accA, Bs0)  PANEL_EPILOGUE(accB, 3)          // T=4
    RDBAR  STAGE_B(Bs0, 6)   WAIT4
    PANEL_COMPUTE(accB, Bs1)  PANEL_EPILOGUE(accA, 4)          // T=5
    RDBAR  STAGE_B(Bs1, 7)   WAIT4
    PANEL_COMPUTE(accA, Bs0)  PANEL_EPILOGUE(accB, 5)          // T=6
    RDBAR  STAGE_B(Bs0, 8)   WAIT4
    PANEL_COMPUTE(accB, Bs1)  PANEL_EPILOGUE(accA, 6)          // T=7
    RDBAR  STAGE_B(Bs1, 9)   WAIT4
    PANEL_COMPUTE(accA, Bs0)  PANEL_EPILOGUE(accB, 7)          // T=8
    RDBAR  STAGE_B(Bs0, 10)  WAIT4
    PANEL_COMPUTE(accB, Bs1)  PANEL_EPILOGUE(accA, 8)          // T=9
    RDBAR  STAGE_B(Bs1, 11)  WAIT4
    PANEL_COMPUTE(accA, Bs0)  PANEL_EPILOGUE(accB, 9)          // T=10
    RDBAR  STAGE_B(Bs0, 12)  WAIT4
    PANEL_COMPUTE(accB, Bs1)  PANEL_EPILOGUE(accA, 10)         // T=11
    RDBAR  STAGE_B(Bs1, 13)  WAIT4
    PANEL_COMPUTE(accA, Bs0)  PANEL_EPILOGUE(accB, 11)         // T=12
    RDBAR  STAGE_B(Bs0, 14)  WAIT4
    PANEL_COMPUTE(accB, Bs1)  PANEL_EPILOGUE(accA, 12)         // T=13
    RDBAR  STAGE_B(Bs1, 15)  WAIT4
    PANEL_COMPUTE(accA, Bs0)  PANEL_EPILOGUE(accB, 13)         // T=14
    RDBAR  WAIT0
    PANEL_COMPUTE(accB, Bs1)  PANEL_EPILOGUE(accA, 14)         // T=15
    PANEL_EPILOGUE(accB, 15)

    // v = ln2*Σm + Σe + diag
    float v = fmaf(LN2, sm[0] + sm[1], se[0] + se[1] + ld);

    // wave reduce then block reduce
#pragma unroll
    for (int off = 32; off; off >>= 1)
        v += __shfl_down(v, off);
    if (lane == 0) wsum[wid] = v;
    __syncthreads();
    if (tid == 0) {
        float t = wsum[0] + wsum[1] + wsum[2] + wsum[3];
        atomicAdd(out, t * (1.0f / ((float)Nn * (float)Nn)));
    }
#undef STAGE_B
#undef PANEL_COMPUTE
#undef PANEL_EPILOGUE
#undef RDBAR
#undef WAIT4
#undef WAIT0
}

extern "C" void kernel_launch(void* const* d_in, const int* in_sizes, int n_in,
                              void* d_out, int out_size, void* d_ws, size_t ws_size,
                              hipStream_t stream) {
    const float* za   = (const float*)d_in[0];
    const float* zb   = (const float*)d_in[1];
    const float* bias = (const float*)d_in[2];

    unsigned char* wa = (unsigned char*)d_ws;
    unsigned char* wb = wa + (size_t)Nn * Dd;

    // zero the output accumulator (harness does not re-poison between replays)
    hipMemsetAsync(d_out, 0, sizeof(float), stream);

    // fp32 -> fp8 pre-pass (A pre-scaled by log2e)
    cvt_kernel<<<dim3(Nn * Dd / 2048), 256, 0, stream>>>(
        (const float4*)za, (const float4*)zb, (int2*)wa, (int2*)wb);

    // fused GEMM + loss: 64 M-tiles x 16 N-supertiles = 1024 blocks, 256 thr
    siglip_kernel<<<dim3(1024), 256, 0, stream>>>(wa, wb, bias, (float*)d_out);
}

// Round 22
// 163.814 us; speedup vs baseline: 4.8337x; 4.8337x over previous
//
#include <hip/hip_runtime.h>
#include <hip/hip_bf16.h>

#define Nn 16384
#define Dd 256
#define L2E 1.4426950408889634f
#define LN2 0.6931471805599453f

typedef __attribute__((ext_vector_type(8))) int int8v;
typedef __attribute__((ext_vector_type(16))) float f32x16;
typedef __attribute__((ext_vector_type(2))) float f32x2;

__device__ inline void gload_lds16(const void* g, void* l) {
    __builtin_amdgcn_global_load_lds(
        (const __attribute__((address_space(1))) void*)g,
        (__attribute__((address_space(3))) void*)l, 16, 0, 0);
}

// fp32 -> fp8 e4m3 (HW RNE). A pre-scaled by log2e: epilogue softplus works in
// exp2/log2 domain with no per-element muls.
__global__ __launch_bounds__(256) void cvt_kernel(
        const float4* __restrict__ a, const float4* __restrict__ b,
        int2* __restrict__ oa, int2* __restrict__ ob) {
    int i = blockIdx.x * 256 + threadIdx.x;
    float4 a0 = a[2 * i], a1 = a[2 * i + 1];
    float4 b0 = b[2 * i], b1 = b[2 * i + 1];
    int alo = __builtin_amdgcn_cvt_pk_fp8_f32(a0.x * L2E, a0.y * L2E, 0, false);
    alo     = __builtin_amdgcn_cvt_pk_fp8_f32(a0.z * L2E, a0.w * L2E, alo, true);
    int ahi = __builtin_amdgcn_cvt_pk_fp8_f32(a1.x * L2E, a1.y * L2E, 0, false);
    ahi     = __builtin_amdgcn_cvt_pk_fp8_f32(a1.z * L2E, a1.w * L2E, ahi, true);
    int blo = __builtin_amdgcn_cvt_pk_fp8_f32(b0.x, b0.y, 0, false);
    blo     = __builtin_amdgcn_cvt_pk_fp8_f32(b0.z, b0.w, blo, true);
    int bhi = __builtin_amdgcn_cvt_pk_fp8_f32(b1.x, b1.y, 0, false);
    bhi     = __builtin_amdgcn_cvt_pk_fp8_f32(b1.z, b1.w, bhi, true);
    oa[i] = make_int2(alo, ahi);
    ob[i] = make_int2(blo, bhi);
}

// 2x ds_read_b128 of one lane's 32 contiguous K-bytes from a [rows][256B]
// full-K LDS tile, XOR-deswizzled (16 chunks/row, chunk ^= row&15).
// Measured ZERO bank conflicts (R8-R20). LDS dest LINEAR (rule #21);
// swizzle lives on the global SOURCE side only.
__device__ inline int8v read_frag256(const unsigned char* base, int rr, int cb) {
    int x = rr & 15;
    int4 lo = *(const int4*)&base[rr * 256 + ((cb ^ x) * 16)];
    int4 hi = *(const int4*)&base[rr * 256 + (((cb + 1) ^ x) * 16)];
    int8v r;
    r[0] = lo.x; r[1] = lo.y; r[2] = lo.z; r[3] = lo.w;
    r[4] = hi.x; r[5] = hi.y; r[6] = hi.z; r[7] = hi.w;
    return r;
}

// Fused MX-fp8 GEMM (sim' = log2e * za.zb^T, unit e8m0 scales) + siglip loss.
// TERMINAL STRUCTURE (R18/R20): persistent-A pipelined-B, 256 thr = 4 waves
// = 1 wave/SIMD, __launch_bounds__(256,1), ONE acc generation (spill law:
// any 2-generation variant spills — R8/9/12/13/14/19/21, 7/7 failures).
// R22 delta: per-iteration order COMPUTE -> EPILOGUE -> RDBAR -> STAGE ->
// WAIT (R20 had the RDBAR between MFMAs and epilogue, fencing the scheduler
// regions apart so epilogue VALU could never fill the MFMA pipe's issue
// gaps; with both in ONE barrier-free region, early-fragment epilogue
// interleaves with late-fragment MFMAs). B-latency hiding is unaffected:
// WAIT8 waits for loads issued a full iteration earlier (already landed).
__global__ __launch_bounds__(256, 1) void siglip_kernel(
        const unsigned char* __restrict__ ga,   // za*log2e fp8 [16384][256]
        const unsigned char* __restrict__ gb,   // zb fp8 [16384][256]
        const float* __restrict__ bp,           // bias scalar
        float* __restrict__ out) {
    __shared__ unsigned char As[256 * 256];    // 64 KB, full-K A tile
    __shared__ unsigned char Bs0[128 * 256];   // 32 KB, B panel buffer 0
    __shared__ unsigned char Bs1[128 * 256];   // 32 KB, B panel buffer 1
    __shared__ float wsum[4];

    const int tid  = threadIdx.x;
    const int lane = tid & 63;
    const int wid  = tid >> 6;     // 0..3
    const int wm   = wid;          // 64-row slice of the 256-row tile
    const int l31  = lane & 31;
    const int h    = lane >> 5;

    // XCD-chunked bijective swizzle (grid 1024 = 8 XCD x 128); consecutive
    // nid share the A panel (same by) and sweep B -> per-XCD L2 locality.
    const int bid = blockIdx.x;
    const int nid = (bid & 7) * 128 + (bid >> 3);
    const int by  = nid >> 4;      // 0..63  M-tile (256 rows)
    const int bxs = nid & 15;      // 0..15  N-supertile (1024 cols)
    const size_t rowA0 = (size_t)by * 256;
    const int    rB0   = bxs * 1024;

    const float b2 = bp[0] * L2E;

    // ---- stage A once: 16 loads/thread; LDS dest linear, source swizzled ----
#pragma unroll
    for (int p = 0; p < 16; ++p) {
        int c = p * 256 + tid; int row = c >> 4;
        int scl = (c & 15) ^ (row & 15);
        gload_lds16(&ga[(rowA0 + row) * Dd + scl * 16], &As[c * 16]);
    }

#define STAGE_B(DST, T)                                                       \
    {                                                                         \
        _Pragma("unroll")                                                     \
        for (int p = 0; p < 8; ++p) {                                         \
            int c = p * 256 + tid; int row = c >> 4;                          \
            int scl = (c & 15) ^ (row & 15);                                  \
            gload_lds16(&gb[(size_t)(rB0 + (T) * 128 + row) * Dd + scl * 16], \
                        &(DST)[c * 16]);                                      \
        }                                                                     \
    }

    STAGE_B(Bs0, 0)
    STAGE_B(Bs1, 1)

    // outstanding: A(16)+B0(8)+B1(8)=32; wait to <=8 -> A and B0 landed.
    asm volatile("s_waitcnt vmcnt(8)" ::: "memory");
    __builtin_amdgcn_s_barrier();
    asm volatile("" ::: "memory");

    f32x2 sm = {0.f, 0.f}, se = {0.f, 0.f};
    float ld = 0.f;
    const int diagblk = (bxs == (by >> 2));
    const int dtile   = (by & 3);

#pragma unroll 1
    for (int t = 0; t < 8; ++t) {
        const unsigned char* Bb = (t & 1) ? Bs1 : Bs0;
        unsigned char*       Bw = (t & 1) ? Bs1 : Bs0;

        f32x16 acc[2][4];
#pragma unroll
        for (int mf = 0; mf < 2; ++mf)
#pragma unroll
            for (int nf = 0; nf < 4; ++nf)
#pragma unroll
                for (int q = 0; q < 16; ++q) acc[mf][nf][q] = -b2;

        // ---- 4 s-steps of K=64B: 6 ds_reads + 8 MFMAs each ----
#pragma unroll
        for (int s = 0; s < 4; ++s) {
            int cb = s * 4 + h * 2;
            int8v aF0 = read_frag256(As, wm * 64 + l31, cb);
            int8v aF1 = read_frag256(As, wm * 64 + 32 + l31, cb);
#pragma unroll
            for (int nf = 0; nf < 4; ++nf) {
                int8v bF = read_frag256(Bb, nf * 32 + l31, cb);
                acc[0][nf] = __builtin_amdgcn_mfma_scale_f32_32x32x64_f8f6f4(
                    aF0, bF, acc[0][nf], 0, 0, 0, 0x7F7F7F7F, 0, 0x7F7F7F7F);
                acc[1][nf] = __builtin_amdgcn_mfma_scale_f32_32x32x64_f8f6f4(
                    aF1, bF, acc[1][nf], 0, 0, 0, 0x7F7F7F7F, 0, 0x7F7F7F7F);
            }
        }

        // ---- epilogue IN THE SAME REGION as the MFMAs (no barrier between):
        // early-frag epilogue VALU interleaves with late-frag MFMAs.
        // loss/elem(nats) ~= ln2*m + 2^(y-2m), m=max(y,0); y-2m == -|y|.
#pragma unroll
        for (int mf = 0; mf < 2; ++mf)
#pragma unroll
            for (int nf = 0; nf < 4; ++nf)
#pragma unroll
                for (int q = 0; q < 16; q += 2) {
                    f32x2 yv = {acc[mf][nf][q], acc[mf][nf][q + 1]};
                    f32x2 mv = {fmaxf(yv[0], 0.f), fmaxf(yv[1], 0.f)};
                    f32x2 tv = yv - 2.f * mv;      // v_pk_fma -> -|y|
                    sm += mv;                      // v_pk_add_f32
                    f32x2 ev = {__builtin_amdgcn_exp2f(tv[0]),
                                __builtin_amdgcn_exp2f(tv[1])};
                    se += ev;                      // v_pk_add_f32
                }

        // diagonal correction: only on the 2 panels meeting this row-range
        if (diagblk && (t >> 1) == dtile) {
#pragma unroll
            for (int mf = 0; mf < 2; ++mf)
#pragma unroll
                for (int nf = 0; nf < 4; ++nf)
#pragma unroll
                    for (int q = 0; q < 16; ++q) {
                        int i_loc = wm * 64 + mf * 32 + (q & 3) + 8 * (q >> 2) + 4 * h;
                        int jg    = ((t & 1) << 7) + nf * 32 + l31;
                        if (i_loc == jg) {
                            float y  = acc[mf][nf][q];
                            float u  = -(y + 2.f * b2);
                            float ey = __builtin_amdgcn_exp2f(-fabsf(y));
                            float eu = __builtin_amdgcn_exp2f(-fabsf(u));
                            float off = LN2 * fmaxf(y, 0.f) + ey;
                            float dg  = LN2 * fmaxf(u, 0.f) + eu;
                            ld += dg - off;
                        }
                    }
        }

        // all waves done reading this buffer -> safe to re-stage it
        asm volatile("" ::: "memory");
        __builtin_amdgcn_s_barrier();
        asm volatile("" ::: "memory");
        if (t < 6) STAGE_B(Bw, t + 2)

        if (t < 6) {
            asm volatile("s_waitcnt vmcnt(8)" ::: "memory");  // B(t+1) landed
            __builtin_amdgcn_s_barrier();
            asm volatile("" ::: "memory");
        } else if (t == 6) {
            asm volatile("s_waitcnt vmcnt(0)" ::: "memory");  // B7 landed
            __builtin_amdgcn_s_barrier();
            asm volatile("" ::: "memory");
        }
    }

    // v = ln2*Σm + Σe + diag
    float v = fmaf(LN2, sm[0] + sm[1], se[0] + se[1] + ld);

    // wave reduce then block reduce
#pragma unroll
    for (int off = 32; off; off >>= 1)
        v += __shfl_down(v, off);
    if (lane == 0) wsum[wid] = v;
    __syncthreads();
    if (tid == 0) {
        float t = wsum[0] + wsum[1] + wsum[2] + wsum[3];
        atomicAdd(out, t * (1.0f / ((float)Nn * (float)Nn)));
    }
#undef STAGE_B
}

extern "C" void kernel_launch(void* const* d_in, const int* in_sizes, int n_in,
                              void* d_out, int out_size, void* d_ws, size_t ws_size,
                              hipStream_t stream) {
    const float* za   = (const float*)d_in[0];
    const float* zb   = (const float*)d_in[1];
    const float* bias = (const float*)d_in[2];

    unsigned char* wa = (unsigned char*)d_ws;
    unsigned char* wb = wa + (size_t)Nn * Dd;

    // zero the output accumulator (harness does not re-poison between replays)
    hipMemsetAsync(d_out, 0, sizeof(float), stream);

    // fp32 -> fp8 pre-pass (A pre-scaled by log2e)
    cvt_kernel<<<dim3(Nn * Dd / 2048), 256, 0, stream>>>(
        (const float4*)za, (const float4*)zb, (int2*)wa, (int2*)wb);

    // fused GEMM + loss: 64 M-tiles x 16 N-supertiles = 1024 blocks, 256 thr
    siglip_kernel<<<dim3(1024), 256, 0, stream>>>(wa, wb, bias, (float*)d_out);
}

// Round 23
// 131.310 us; speedup vs baseline: 6.0302x; 1.2475x over previous
//
#include <hip/hip_runtime.h>
#include <hip/hip_bf16.h>

#define Nn 16384
#define Dd 256
#define L2E 1.4426950408889634f
#define LN2 0.6931471805599453f

typedef __attribute__((ext_vector_type(8))) int int8v;
typedef __attribute__((ext_vector_type(16))) float f32x16;
typedef __attribute__((ext_vector_type(2))) float f32x2;

__device__ inline void gload_lds16(const void* g, void* l) {
    __builtin_amdgcn_global_load_lds(
        (const __attribute__((address_space(1))) void*)g,
        (__attribute__((address_space(3))) void*)l, 16, 0, 0);
}

// fp32 -> fp8 e4m3 (HW RNE). A pre-scaled by log2e: epilogue softplus works in
// exp2/log2 domain with no per-element muls.
__global__ __launch_bounds__(256) void cvt_kernel(
        const float4* __restrict__ a, const float4* __restrict__ b,
        int2* __restrict__ oa, int2* __restrict__ ob) {
    int i = blockIdx.x * 256 + threadIdx.x;
    float4 a0 = a[2 * i], a1 = a[2 * i + 1];
    float4 b0 = b[2 * i], b1 = b[2 * i + 1];
    int alo = __builtin_amdgcn_cvt_pk_fp8_f32(a0.x * L2E, a0.y * L2E, 0, false);
    alo     = __builtin_amdgcn_cvt_pk_fp8_f32(a0.z * L2E, a0.w * L2E, alo, true);
    int ahi = __builtin_amdgcn_cvt_pk_fp8_f32(a1.x * L2E, a1.y * L2E, 0, false);
    ahi     = __builtin_amdgcn_cvt_pk_fp8_f32(a1.z * L2E, a1.w * L2E, ahi, true);
    int blo = __builtin_amdgcn_cvt_pk_fp8_f32(b0.x, b0.y, 0, false);
    blo     = __builtin_amdgcn_cvt_pk_fp8_f32(b0.z, b0.w, blo, true);
    int bhi = __builtin_amdgcn_cvt_pk_fp8_f32(b1.x, b1.y, 0, false);
    bhi     = __builtin_amdgcn_cvt_pk_fp8_f32(b1.z, b1.w, bhi, true);
    oa[i] = make_int2(alo, ahi);
    ob[i] = make_int2(blo, bhi);
}

// 2x ds_read_b128 of one lane's 32 contiguous K-bytes from a [rows][256B]
// full-K LDS tile, XOR-deswizzled (16 chunks/row, chunk ^= row&15).
// Measured ZERO bank conflicts (R8-R20). LDS dest LINEAR (rule #21);
// swizzle lives on the global SOURCE side only.
__device__ inline int8v read_frag256(const unsigned char* base, int rr, int cb) {
    int x = rr & 15;
    int4 lo = *(const int4*)&base[rr * 256 + ((cb ^ x) * 16)];
    int4 hi = *(const int4*)&base[rr * 256 + (((cb + 1) ^ x) * 16)];
    int8v r;
    r[0] = lo.x; r[1] = lo.y; r[2] = lo.z; r[3] = lo.w;
    r[4] = hi.x; r[5] = hi.y; r[6] = hi.z; r[7] = hi.w;
    return r;
}

// Fused MX-fp8 GEMM (sim' = log2e * za.zb^T, unit e8m0 scales) + siglip loss.
// TERMINAL KERNEL (R20, 130.6 us; reverted after R21/R22 regressions).
// Structure: persistent-A pipelined-B, 256 thr = 4 waves = 1 wave/SIMD,
// __launch_bounds__(256,1). Allocator laws established this session:
//  - exactly ONE live acc generation (2-gen variants spill 7/7:
//    R8/9/12/13/14/19/21, any size, despite fences/AGPR-pins);
//  - arch-VGPR caps at 256 even at 1 wave/SIMD;
//  - epilogue merged into the MFMA scheduler region spills (R22);
//  - barriers fence scheduler regions -> phases add at 1 wave/SIMD.
// Block = 256 M-rows x 1024 N-cols (8 panels of 128). A[256][256B] staged
// once (64KB); B double-buffered (2x32KB), 2 panels ahead, counted vmcnt(8);
// vmcnt(0) only at the last panel. Per-panel packed epilogue:
// loss/elem(nats) ~= ln2*m + 2^(y-2m), m=max(y,0) [y-2m == -|y|; e^2/2
// dropped, absmax 0.031 stable R10-R22]. VGPR=252, WRITE=32B, conflicts=0;
// MFMA-busy matches the 29us MX-fp8 floor exactly (MfmaUtil*dur).
__global__ __launch_bounds__(256, 1) void siglip_kernel(
        const unsigned char* __restrict__ ga,   // za*log2e fp8 [16384][256]
        const unsigned char* __restrict__ gb,   // zb fp8 [16384][256]
        const float* __restrict__ bp,           // bias scalar
        float* __restrict__ out) {
    __shared__ unsigned char As[256 * 256];    // 64 KB, full-K A tile
    __shared__ unsigned char Bs0[128 * 256];   // 32 KB, B panel buffer 0
    __shared__ unsigned char Bs1[128 * 256];   // 32 KB, B panel buffer 1
    __shared__ float wsum[4];

    const int tid  = threadIdx.x;
    const int lane = tid & 63;
    const int wid  = tid >> 6;     // 0..3
    const int wm   = wid;          // 64-row slice of the 256-row tile
    const int l31  = lane & 31;
    const int h    = lane >> 5;

    // XCD-chunked bijective swizzle (grid 1024 = 8 XCD x 128); consecutive
    // nid share the A panel (same by) and sweep B -> per-XCD L2 locality.
    const int bid = blockIdx.x;
    const int nid = (bid & 7) * 128 + (bid >> 3);
    const int by  = nid >> 4;      // 0..63  M-tile (256 rows)
    const int bxs = nid & 15;      // 0..15  N-supertile (1024 cols)
    const size_t rowA0 = (size_t)by * 256;
    const int    rB0   = bxs * 1024;

    const float b2 = bp[0] * L2E;

    // ---- stage A once: 16 loads/thread; LDS dest linear, source swizzled ----
#pragma unroll
    for (int p = 0; p < 16; ++p) {
        int c = p * 256 + tid; int row = c >> 4;
        int scl = (c & 15) ^ (row & 15);
        gload_lds16(&ga[(rowA0 + row) * Dd + scl * 16], &As[c * 16]);
    }

#define STAGE_B(DST, T)                                                       \
    {                                                                         \
        _Pragma("unroll")                                                     \
        for (int p = 0; p < 8; ++p) {                                         \
            int c = p * 256 + tid; int row = c >> 4;                          \
            int scl = (c & 15) ^ (row & 15);                                  \
            gload_lds16(&gb[(size_t)(rB0 + (T) * 128 + row) * Dd + scl * 16], \
                        &(DST)[c * 16]);                                      \
        }                                                                     \
    }

    STAGE_B(Bs0, 0)
    STAGE_B(Bs1, 1)

    // outstanding: A(16)+B0(8)+B1(8)=32; wait to <=8 -> A and B0 landed.
    asm volatile("s_waitcnt vmcnt(8)" ::: "memory");
    __builtin_amdgcn_s_barrier();
    asm volatile("" ::: "memory");

    f32x2 sm = {0.f, 0.f}, se = {0.f, 0.f};
    float ld = 0.f;
    const int diagblk = (bxs == (by >> 2));
    const int dtile   = (by & 3);

#pragma unroll 1
    for (int t = 0; t < 8; ++t) {
        const unsigned char* Bb = (t & 1) ? Bs1 : Bs0;
        unsigned char*       Bw = (t & 1) ? Bs1 : Bs0;

        f32x16 acc[2][4];
#pragma unroll
        for (int mf = 0; mf < 2; ++mf)
#pragma unroll
            for (int nf = 0; nf < 4; ++nf)
#pragma unroll
                for (int q = 0; q < 16; ++q) acc[mf][nf][q] = -b2;

        // ---- 4 s-steps of K=64B: 6 ds_reads + 8 MFMAs each ----
#pragma unroll
        for (int s = 0; s < 4; ++s) {
            int cb = s * 4 + h * 2;
            int8v aF0 = read_frag256(As, wm * 64 + l31, cb);
            int8v aF1 = read_frag256(As, wm * 64 + 32 + l31, cb);
#pragma unroll
            for (int nf = 0; nf < 4; ++nf) {
                int8v bF = read_frag256(Bb, nf * 32 + l31, cb);
                acc[0][nf] = __builtin_amdgcn_mfma_scale_f32_32x32x64_f8f6f4(
                    aF0, bF, acc[0][nf], 0, 0, 0, 0x7F7F7F7F, 0, 0x7F7F7F7F);
                acc[1][nf] = __builtin_amdgcn_mfma_scale_f32_32x32x64_f8f6f4(
                    aF1, bF, acc[1][nf], 0, 0, 0, 0x7F7F7F7F, 0, 0x7F7F7F7F);
            }
        }

        // all waves done reading this buffer -> safe to re-stage it
        asm volatile("" ::: "memory");
        __builtin_amdgcn_s_barrier();
        asm volatile("" ::: "memory");
        if (t < 6) STAGE_B(Bw, t + 2)

        // ---- per-panel epilogue (packed, cheap form; overlaps B-flight) ----
        // loss/elem(nats) ~= ln2*m + 2^(y-2m), m=max(y,0); y-2m == -|y|.
#pragma unroll
        for (int mf = 0; mf < 2; ++mf)
#pragma unroll
            for (int nf = 0; nf < 4; ++nf)
#pragma unroll
                for (int q = 0; q < 16; q += 2) {
                    f32x2 yv = {acc[mf][nf][q], acc[mf][nf][q + 1]};
                    f32x2 mv = {fmaxf(yv[0], 0.f), fmaxf(yv[1], 0.f)};
                    f32x2 tv = yv - 2.f * mv;      // v_pk_fma -> -|y|
                    sm += mv;                      // v_pk_add_f32
                    f32x2 ev = {__builtin_amdgcn_exp2f(tv[0]),
                                __builtin_amdgcn_exp2f(tv[1])};
                    se += ev;                      // v_pk_add_f32
                }

        // diagonal correction: only on the 2 panels meeting this row-range
        if (diagblk && (t >> 1) == dtile) {
#pragma unroll
            for (int mf = 0; mf < 2; ++mf)
#pragma unroll
                for (int nf = 0; nf < 4; ++nf)
#pragma unroll
                    for (int q = 0; q < 16; ++q) {
                        int i_loc = wm * 64 + mf * 32 + (q & 3) + 8 * (q >> 2) + 4 * h;
                        int jg    = ((t & 1) << 7) + nf * 32 + l31;
                        if (i_loc == jg) {
                            float y  = acc[mf][nf][q];
                            float u  = -(y + 2.f * b2);
                            float ey = __builtin_amdgcn_exp2f(-fabsf(y));
                            float eu = __builtin_amdgcn_exp2f(-fabsf(u));
                            float off = LN2 * fmaxf(y, 0.f) + ey;
                            float dg  = LN2 * fmaxf(u, 0.f) + eu;
                            ld += dg - off;
                        }
                    }
        }

        if (t < 6) {
            asm volatile("s_waitcnt vmcnt(8)" ::: "memory");  // B(t+1) landed
            __builtin_amdgcn_s_barrier();
            asm volatile("" ::: "memory");
        } else if (t == 6) {
            asm volatile("s_waitcnt vmcnt(0)" ::: "memory");  // B7 landed
            __builtin_amdgcn_s_barrier();
            asm volatile("" ::: "memory");
        }
    }

    // v = ln2*Σm + Σe + diag
    float v = fmaf(LN2, sm[0] + sm[1], se[0] + se[1] + ld);

    // wave reduce then block reduce
#pragma unroll
    for (int off = 32; off; off >>= 1)
        v += __shfl_down(v, off);
    if (lane == 0) wsum[wid] = v;
    __syncthreads();
    if (tid == 0) {
        float t = wsum[0] + wsum[1] + wsum[2] + wsum[3];
        atomicAdd(out, t * (1.0f / ((float)Nn * (float)Nn)));
    }
#undef STAGE_B
}

extern "C" void kernel_launch(void* const* d_in, const int* in_sizes, int n_in,
                              void* d_out, int out_size, void* d_ws, size_t ws_size,
                              hipStream_t stream) {
    const float* za   = (const float*)d_in[0];
    const float* zb   = (const float*)d_in[1];
    const float* bias = (const float*)d_in[2];

    unsigned char* wa = (unsigned char*)d_ws;
    unsigned char* wb = wa + (size_t)Nn * Dd;

    // zero the output accumulator (harness does not re-poison between replays)
    hipMemsetAsync(d_out, 0, sizeof(float), stream);

    // fp32 -> fp8 pre-pass (A pre-scaled by log2e)
    cvt_kernel<<<dim3(Nn * Dd / 2048), 256, 0, stream>>>(
        (const float4*)za, (const float4*)zb, (int2*)wa, (int2*)wb);

    // fused GEMM + loss: 64 M-tiles x 16 N-supertiles = 1024 blocks, 256 thr
    siglip_kernel<<<dim3(1024), 256, 0, stream>>>(wa, wb, bias, (float*)d_out);
}

// Round 24
// 126.554 us; speedup vs baseline: 6.2568x; 1.0376x over previous
//
#include <hip/hip_runtime.h>
#include <hip/hip_bf16.h>

#define Nn 16384
#define Dd 256
#define L2E 1.4426950408889634f
#define LN2 0.6931471805599453f

typedef __attribute__((ext_vector_type(8))) int int8v;
typedef __attribute__((ext_vector_type(16))) float f32x16;
typedef __attribute__((ext_vector_type(2))) float f32x2;

__device__ inline void gload_lds16(const void* g, void* l) {
    __builtin_amdgcn_global_load_lds(
        (const __attribute__((address_space(1))) void*)g,
        (__attribute__((address_space(3))) void*)l, 16, 0, 0);
}

// fp32 -> fp8 e4m3 (HW RNE). A pre-scaled by log2e: epilogue softplus works in
// exp2/log2 domain with no per-element muls.
__global__ __launch_bounds__(256) void cvt_kernel(
        const float4* __restrict__ a, const float4* __restrict__ b,
        int2* __restrict__ oa, int2* __restrict__ ob) {
    int i = blockIdx.x * 256 + threadIdx.x;
    float4 a0 = a[2 * i], a1 = a[2 * i + 1];
    float4 b0 = b[2 * i], b1 = b[2 * i + 1];
    int alo = __builtin_amdgcn_cvt_pk_fp8_f32(a0.x * L2E, a0.y * L2E, 0, false);
    alo     = __builtin_amdgcn_cvt_pk_fp8_f32(a0.z * L2E, a0.w * L2E, alo, true);
    int ahi = __builtin_amdgcn_cvt_pk_fp8_f32(a1.x * L2E, a1.y * L2E, 0, false);
    ahi     = __builtin_amdgcn_cvt_pk_fp8_f32(a1.z * L2E, a1.w * L2E, ahi, true);
    int blo = __builtin_amdgcn_cvt_pk_fp8_f32(b0.x, b0.y, 0, false);
    blo     = __builtin_amdgcn_cvt_pk_fp8_f32(b0.z, b0.w, blo, true);
    int bhi = __builtin_amdgcn_cvt_pk_fp8_f32(b1.x, b1.y, 0, false);
    bhi     = __builtin_amdgcn_cvt_pk_fp8_f32(b1.z, b1.w, bhi, true);
    oa[i] = make_int2(alo, ahi);
    ob[i] = make_int2(blo, bhi);
}

// 2x ds_read_b128 of one lane's 32 contiguous K-bytes from a [rows][256B]
// full-K LDS tile, XOR-deswizzled (16 chunks/row, chunk ^= row&15).
// Measured ZERO bank conflicts (R8-R23). LDS dest LINEAR (rule #21);
// swizzle lives on the global SOURCE side only.
__device__ inline int8v read_frag256(const unsigned char* base, int rr, int cb) {
    int x = rr & 15;
    int4 lo = *(const int4*)&base[rr * 256 + ((cb ^ x) * 16)];
    int4 hi = *(const int4*)&base[rr * 256 + (((cb + 1) ^ x) * 16)];
    int8v r;
    r[0] = lo.x; r[1] = lo.y; r[2] = lo.z; r[3] = lo.w;
    r[4] = hi.x; r[5] = hi.y; r[6] = hi.z; r[7] = hi.w;
    return r;
}

// Fused MX-fp8 GEMM (sim' = log2e * za.zb^T, unit e8m0 scales) + siglip loss.
// R24: R20's persistent-A pipelined-B loop at HALF footprint so TWO blocks
// co-reside per CU (the untested combination: co-residency attempts R7/R11/
// R16 used short-lived 2-8us blocks where dispatch latency blocks overlap;
// R18/R20's 33us looped blocks are long-lived but 128KB LDS forbade 2/CU).
// Block = 128 M-rows x 1024 N-cols (16 panels of 64). A[128][256B] = 32KB
// staged once; B dbuf 2x16KB -> 65.5KB total -> 2 blocks/CU by LDS.
// 256 thr = 4 waves (2M x 2N), wave tile 64x32 -> acc[2] f32x16 = 32 AGPR,
// ONE generation (spill law). __launch_bounds__(256,2): cap 256/wave,
// demand ~170. Cross-block: one block's epilogue/waits overlap the other's
// MFMAs -> attacks the phase-addition behind MfmaUtil=22%.
__global__ __launch_bounds__(256, 2) void siglip_kernel(
        const unsigned char* __restrict__ ga,   // za*log2e fp8 [16384][256]
        const unsigned char* __restrict__ gb,   // zb fp8 [16384][256]
        const float* __restrict__ bp,           // bias scalar
        float* __restrict__ out) {
    __shared__ unsigned char As[128 * 256];   // 32 KB, full-K A tile
    __shared__ unsigned char Bs0[64 * 256];   // 16 KB, B panel buffer 0
    __shared__ unsigned char Bs1[64 * 256];   // 16 KB, B panel buffer 1
    __shared__ float wsum[4];

    const int tid  = threadIdx.x;
    const int lane = tid & 63;
    const int wid  = tid >> 6;     // 0..3
    const int wm   = wid >> 1;     // 0..1 -> 64-row slice of the 128-row tile
    const int wn   = wid & 1;      // 0..1 -> 32-col slice of the 64-col panel
    const int l31  = lane & 31;
    const int h    = lane >> 5;

    // XCD-chunked bijective swizzle (grid 2048 = 8 XCD x 256); consecutive
    // nid share the A panel (same by) and sweep B -> per-XCD L2 locality.
    const int bid = blockIdx.x;
    const int nid = (bid & 7) * 256 + (bid >> 3);
    const int by  = nid >> 4;      // 0..127  M-tile (128 rows)
    const int bxs = nid & 15;      // 0..15   N-supertile (1024 cols)
    const size_t rowA0 = (size_t)by * 128;
    const int    rB0   = bxs * 1024;

    const float b2 = bp[0] * L2E;
    const int diagblk = (bxs == (by >> 3));
    const int dby7    = by & 7;    // which panel-pair holds this block's diag

    // ---- stage A once: 8 loads/thread; LDS dest linear, source swizzled ----
#pragma unroll
    for (int p = 0; p < 8; ++p) {
        int c = p * 256 + tid; int row = c >> 4;
        int scl = (c & 15) ^ (row & 15);
        gload_lds16(&ga[(rowA0 + row) * Dd + scl * 16], &As[c * 16]);
    }

    // B panel = 64 rows x 256B = 1024 chunks -> 4 loads/thread.
#define STAGE_B(DST, T)                                                       \
    {                                                                         \
        _Pragma("unroll")                                                     \
        for (int p = 0; p < 4; ++p) {                                         \
            int c = p * 256 + tid; int row = c >> 4;                          \
            int scl = (c & 15) ^ (row & 15);                                  \
            gload_lds16(&gb[(size_t)(rB0 + (T) * 64 + row) * Dd + scl * 16],  \
                        &(DST)[c * 16]);                                      \
        }                                                                     \
    }

    STAGE_B(Bs0, 0)
    STAGE_B(Bs1, 1)

    // outstanding: A(8)+B0(4)+B1(4)=16; wait to <=4 -> A and B0 landed.
    asm volatile("s_waitcnt vmcnt(4)" ::: "memory");
    __builtin_amdgcn_s_barrier();
    asm volatile("" ::: "memory");

    f32x2 sm = {0.f, 0.f}, se = {0.f, 0.f};
    float ld = 0.f;

#pragma unroll 1
    for (int t = 0; t < 16; ++t) {
        const unsigned char* Bb = (t & 1) ? Bs1 : Bs0;
        unsigned char*       Bw = (t & 1) ? Bs1 : Bs0;

        f32x16 acc[2];
#pragma unroll
        for (int mf = 0; mf < 2; ++mf)
#pragma unroll
            for (int q = 0; q < 16; ++q) acc[mf][q] = -b2;

        // ---- 4 s-steps of K=64B: 3 ds_reads + 2 MFMAs each ----
#pragma unroll
        for (int s = 0; s < 4; ++s) {
            int cb = s * 4 + h * 2;
            int8v aF0 = read_frag256(As, wm * 64 + l31, cb);
            int8v aF1 = read_frag256(As, wm * 64 + 32 + l31, cb);
            int8v bF  = read_frag256(Bb, wn * 32 + l31, cb);
            acc[0] = __builtin_amdgcn_mfma_scale_f32_32x32x64_f8f6f4(
                aF0, bF, acc[0], 0, 0, 0, 0x7F7F7F7F, 0, 0x7F7F7F7F);
            acc[1] = __builtin_amdgcn_mfma_scale_f32_32x32x64_f8f6f4(
                aF1, bF, acc[1], 0, 0, 0, 0x7F7F7F7F, 0, 0x7F7F7F7F);
        }

        // all waves done reading this buffer -> safe to re-stage it
        asm volatile("" ::: "memory");
        __builtin_amdgcn_s_barrier();
        asm volatile("" ::: "memory");
        if (t < 14) STAGE_B(Bw, t + 2)

        // ---- per-panel epilogue (packed; overlaps B-flight) ----
        // loss/elem(nats) ~= ln2*m + 2^(y-2m), m=max(y,0); y-2m == -|y|.
#pragma unroll
        for (int mf = 0; mf < 2; ++mf)
#pragma unroll
            for (int q = 0; q < 16; q += 2) {
                f32x2 yv = {acc[mf][q], acc[mf][q + 1]};
                f32x2 mv = {fmaxf(yv[0], 0.f), fmaxf(yv[1], 0.f)};
                f32x2 tv = yv - 2.f * mv;      // v_pk_fma -> -|y|
                sm += mv;                      // v_pk_add_f32
                f32x2 ev = {__builtin_amdgcn_exp2f(tv[0]),
                            __builtin_amdgcn_exp2f(tv[1])};
                se += ev;                      // v_pk_add_f32
            }

        // Diagonal correction. Block diag cols live in panels 2*(by&7) and
        // 2*(by&7)+1; panel T's diag rows are the wm==(T&1) slice; within it
        // row = mf*32+rq must equal panel col = wn*32+l31 -> mf==wn, rq==l31.
        if (diagblk && (t >> 1) == dby7 && wm == (t & 1)) {
            const int mf = wn;
#pragma unroll
            for (int q = 0; q < 16; ++q) {
                int rq = (q & 3) + 8 * (q >> 2) + 4 * h;
                if (rq == l31) {
                    float y  = acc[mf][q];
                    float u  = -(y + 2.f * b2);
                    float ey = __builtin_amdgcn_exp2f(-fabsf(y));
                    float eu = __builtin_amdgcn_exp2f(-fabsf(u));
                    float off = LN2 * fmaxf(y, 0.f) + ey;
                    float dg  = LN2 * fmaxf(u, 0.f) + eu;
                    ld += dg - off;
                }
            }
        }

        if (t < 14) {
            asm volatile("s_waitcnt vmcnt(4)" ::: "memory");  // B(t+1) landed
            __builtin_amdgcn_s_barrier();
            asm volatile("" ::: "memory");
        } else if (t == 14) {
            asm volatile("s_waitcnt vmcnt(0)" ::: "memory");  // B15 landed
            __builtin_amdgcn_s_barrier();
            asm volatile("" ::: "memory");
        }
    }

    // v = ln2*Σm + Σe + diag
    float v = fmaf(LN2, sm[0] + sm[1], se[0] + se[1] + ld);

    // wave reduce then block reduce
#pragma unroll
    for (int off = 32; off; off >>= 1)
        v += __shfl_down(v, off);
    if (lane == 0) wsum[wid] = v;
    __syncthreads();
    if (tid == 0) {
        float t = wsum[0] + wsum[1] + wsum[2] + wsum[3];
        atomicAdd(out, t * (1.0f / ((float)Nn * (float)Nn)));
    }
#undef STAGE_B
}

extern "C" void kernel_launch(void* const* d_in, const int* in_sizes, int n_in,
                              void* d_out, int out_size, void* d_ws, size_t ws_size,
                              hipStream_t stream) {
    const float* za   = (const float*)d_in[0];
    const float* zb   = (const float*)d_in[1];
    const float* bias = (const float*)d_in[2];

    unsigned char* wa = (unsigned char*)d_ws;
    unsigned char* wb = wa + (size_t)Nn * Dd;

    // zero the output accumulator (harness does not re-poison between replays)
    hipMemsetAsync(d_out, 0, sizeof(float), stream);

    // fp32 -> fp8 pre-pass (A pre-scaled by log2e)
    cvt_kernel<<<dim3(Nn * Dd / 2048), 256, 0, stream>>>(
        (const float4*)za, (const float4*)zb, (int2*)wa, (int2*)wb);

    // fused GEMM + loss: 128 M-tiles x 16 N-supertiles = 2048 blocks, 256 thr
    siglip_kernel<<<dim3(2048), 256, 0, stream>>>(wa, wb, bias, (float*)d_out);
}

// Round 25
// 121.979 us; speedup vs baseline: 6.4915x; 1.0375x over previous
//
#include <hip/hip_runtime.h>
#include <hip/hip_bf16.h>

#define Nn 16384
#define Dd 256
#define L2E 1.4426950408889634f
#define LN2 0.6931471805599453f

typedef __attribute__((ext_vector_type(8))) int int8v;
typedef __attribute__((ext_vector_type(16))) float f32x16;
typedef __attribute__((ext_vector_type(2))) float f32x2;

__device__ inline void gload_lds16(const void* g, void* l) {
    __builtin_amdgcn_global_load_lds(
        (const __attribute__((address_space(1))) void*)g,
        (__attribute__((address_space(3))) void*)l, 16, 0, 0);
}

// fp32 -> fp8 e4m3 (HW RNE). A pre-scaled by log2e: epilogue softplus works in
// exp2/log2 domain with no per-element muls.
__global__ __launch_bounds__(256) void cvt_kernel(
        const float4* __restrict__ a, const float4* __restrict__ b,
        int2* __restrict__ oa, int2* __restrict__ ob) {
    int i = blockIdx.x * 256 + threadIdx.x;
    float4 a0 = a[2 * i], a1 = a[2 * i + 1];
    float4 b0 = b[2 * i], b1 = b[2 * i + 1];
    int alo = __builtin_amdgcn_cvt_pk_fp8_f32(a0.x * L2E, a0.y * L2E, 0, false);
    alo     = __builtin_amdgcn_cvt_pk_fp8_f32(a0.z * L2E, a0.w * L2E, alo, true);
    int ahi = __builtin_amdgcn_cvt_pk_fp8_f32(a1.x * L2E, a1.y * L2E, 0, false);
    ahi     = __builtin_amdgcn_cvt_pk_fp8_f32(a1.z * L2E, a1.w * L2E, ahi, true);
    int blo = __builtin_amdgcn_cvt_pk_fp8_f32(b0.x, b0.y, 0, false);
    blo     = __builtin_amdgcn_cvt_pk_fp8_f32(b0.z, b0.w, blo, true);
    int bhi = __builtin_amdgcn_cvt_pk_fp8_f32(b1.x, b1.y, 0, false);
    bhi     = __builtin_amdgcn_cvt_pk_fp8_f32(b1.z, b1.w, bhi, true);
    oa[i] = make_int2(alo, ahi);
    ob[i] = make_int2(blo, bhi);
}

// 2x ds_read_b128 of one lane's 32 contiguous K-bytes from a [rows][256B]
// full-K LDS tile, XOR-deswizzled (16 chunks/row, chunk ^= row&15).
// Measured ZERO bank conflicts (R8-R24). LDS dest LINEAR (rule #21);
// swizzle lives on the global SOURCE side only.
__device__ inline int8v read_frag256(const unsigned char* base, int rr, int cb) {
    int x = rr & 15;
    int4 lo = *(const int4*)&base[rr * 256 + ((cb ^ x) * 16)];
    int4 hi = *(const int4*)&base[rr * 256 + (((cb + 1) ^ x) * 16)];
    int8v r;
    r[0] = lo.x; r[1] = lo.y; r[2] = lo.z; r[3] = lo.w;
    r[4] = hi.x; r[5] = hi.y; r[6] = hi.z; r[7] = hi.w;
    return r;
}

#define MFMA_(A, B, C) __builtin_amdgcn_mfma_scale_f32_32x32x64_f8f6f4(       \
    (A), (B), (C), 0, 0, 0, 0x7F7F7F7F, 0, 0x7F7F7F7F)

// Fused MX-fp8 GEMM (sim' = log2e * za.zb^T, unit e8m0 scales) + siglip loss.
// R25 = R24 (2-blocks/CU co-resident loop: 128Mx1024N, A 32KB staged once,
// B dbuf 2x16KB, counted vmcnt(4)) + two VALU cuts (VALU is the binding
// pipe: ~53us busy vs 29us MFMA floor at R24):
//  1. bias_acc C-operand: read-only f32x16 = -b2 initialized ONCE; each
//     panel's FIRST MFMA takes it as C -> deletes the per-panel 32x v_mov
//     acc-init (1 inst/elem, ~7us device-wide). Read-only -> not a second
//     acc generation -> spill law respected.
//  2. epilogue: exp2(-fabsf(y)) direct (VOP1 -abs modifier is free),
//     dropping the tv=y-2m pk_fma (-1 VALU per elem-pair).
__global__ __launch_bounds__(256, 2) void siglip_kernel(
        const unsigned char* __restrict__ ga,   // za*log2e fp8 [16384][256]
        const unsigned char* __restrict__ gb,   // zb fp8 [16384][256]
        const float* __restrict__ bp,           // bias scalar
        float* __restrict__ out) {
    __shared__ unsigned char As[128 * 256];   // 32 KB, full-K A tile
    __shared__ unsigned char Bs0[64 * 256];   // 16 KB, B panel buffer 0
    __shared__ unsigned char Bs1[64 * 256];   // 16 KB, B panel buffer 1
    __shared__ float wsum[4];

    const int tid  = threadIdx.x;
    const int lane = tid & 63;
    const int wid  = tid >> 6;     // 0..3
    const int wm   = wid >> 1;     // 0..1 -> 64-row slice of the 128-row tile
    const int wn   = wid & 1;      // 0..1 -> 32-col slice of the 64-col panel
    const int l31  = lane & 31;
    const int h    = lane >> 5;

    // XCD-chunked bijective swizzle (grid 2048 = 8 XCD x 256); consecutive
    // nid share the A panel (same by) and sweep B -> per-XCD L2 locality.
    const int bid = blockIdx.x;
    const int nid = (bid & 7) * 256 + (bid >> 3);
    const int by  = nid >> 4;      // 0..127  M-tile (128 rows)
    const int bxs = nid & 15;      // 0..15   N-supertile (1024 cols)
    const size_t rowA0 = (size_t)by * 128;
    const int    rB0   = bxs * 1024;

    const float b2 = bp[0] * L2E;
    const int diagblk = (bxs == (by >> 3));
    const int dby7    = by & 7;    // which panel-pair holds this block's diag

    // ---- stage A once: 8 loads/thread; LDS dest linear, source swizzled ----
#pragma unroll
    for (int p = 0; p < 8; ++p) {
        int c = p * 256 + tid; int row = c >> 4;
        int scl = (c & 15) ^ (row & 15);
        gload_lds16(&ga[(rowA0 + row) * Dd + scl * 16], &As[c * 16]);
    }

    // B panel = 64 rows x 256B = 1024 chunks -> 4 loads/thread.
#define STAGE_B(DST, T)                                                       \
    {                                                                         \
        _Pragma("unroll")                                                     \
        for (int p = 0; p < 4; ++p) {                                         \
            int c = p * 256 + tid; int row = c >> 4;                          \
            int scl = (c & 15) ^ (row & 15);                                  \
            gload_lds16(&gb[(size_t)(rB0 + (T) * 64 + row) * Dd + scl * 16],  \
                        &(DST)[c * 16]);                                      \
        }                                                                     \
    }

    STAGE_B(Bs0, 0)
    STAGE_B(Bs1, 1)

    // read-only bias accumulator: initialized ONCE, used as the C operand of
    // every panel's first MFMA (replaces per-panel acc init).
    f32x16 bias_acc;
#pragma unroll
    for (int q = 0; q < 16; ++q) bias_acc[q] = -b2;

    // outstanding: A(8)+B0(4)+B1(4)=16; wait to <=4 -> A and B0 landed.
    asm volatile("s_waitcnt vmcnt(4)" ::: "memory");
    __builtin_amdgcn_s_barrier();
    asm volatile("" ::: "memory");

    f32x2 sm = {0.f, 0.f}, se = {0.f, 0.f};
    float ld = 0.f;

#pragma unroll 1
    for (int t = 0; t < 16; ++t) {
        const unsigned char* Bb = (t & 1) ? Bs1 : Bs0;
        unsigned char*       Bw = (t & 1) ? Bs1 : Bs0;

        f32x16 acc[2];

        // ---- s=0: first MFMA consumes bias_acc as C (no acc init) ----
        {
            int cb = h * 2;
            int8v aF0 = read_frag256(As, wm * 64 + l31, cb);
            int8v aF1 = read_frag256(As, wm * 64 + 32 + l31, cb);
            int8v bF  = read_frag256(Bb, wn * 32 + l31, cb);
            acc[0] = MFMA_(aF0, bF, bias_acc);
            acc[1] = MFMA_(aF1, bF, bias_acc);
        }
        // ---- s=1..3 accumulate ----
#pragma unroll
        for (int s = 1; s < 4; ++s) {
            int cb = s * 4 + h * 2;
            int8v aF0 = read_frag256(As, wm * 64 + l31, cb);
            int8v aF1 = read_frag256(As, wm * 64 + 32 + l31, cb);
            int8v bF  = read_frag256(Bb, wn * 32 + l31, cb);
            acc[0] = MFMA_(aF0, bF, acc[0]);
            acc[1] = MFMA_(aF1, bF, acc[1]);
        }

        // all waves done reading this buffer -> safe to re-stage it
        asm volatile("" ::: "memory");
        __builtin_amdgcn_s_barrier();
        asm volatile("" ::: "memory");
        if (t < 14) STAGE_B(Bw, t + 2)

        // ---- per-panel epilogue (packed; overlaps B-flight) ----
        // loss/elem(nats) ~= ln2*max(y,0) + 2^-|y| (exp2 -abs modifier free)
#pragma unroll
        for (int mf = 0; mf < 2; ++mf)
#pragma unroll
            for (int q = 0; q < 16; q += 2) {
                f32x2 yv = {acc[mf][q], acc[mf][q + 1]};
                f32x2 mv = {fmaxf(yv[0], 0.f), fmaxf(yv[1], 0.f)};
                sm += mv;                      // v_pk_add_f32
                f32x2 ev = {__builtin_amdgcn_exp2f(-fabsf(yv[0])),
                            __builtin_amdgcn_exp2f(-fabsf(yv[1]))};
                se += ev;                      // v_pk_add_f32
            }

        // Diagonal correction. Block diag cols live in panels 2*(by&7) and
        // 2*(by&7)+1; panel T's diag rows are the wm==(T&1) slice; within it
        // row = mf*32+rq must equal panel col = wn*32+l31 -> mf==wn, rq==l31.
        if (diagblk && (t >> 1) == dby7 && wm == (t & 1)) {
            const int mf = wn;
#pragma unroll
            for (int q = 0; q < 16; ++q) {
                int rq = (q & 3) + 8 * (q >> 2) + 4 * h;
                if (rq == l31) {
                    float y  = acc[mf][q];
                    float u  = -(y + 2.f * b2);
                    float ey = __builtin_amdgcn_exp2f(-fabsf(y));
                    float eu = __builtin_amdgcn_exp2f(-fabsf(u));
                    float off = LN2 * fmaxf(y, 0.f) + ey;
                    float dg  = LN2 * fmaxf(u, 0.f) + eu;
                    ld += dg - off;
                }
            }
        }

        if (t < 14) {
            asm volatile("s_waitcnt vmcnt(4)" ::: "memory");  // B(t+1) landed
            __builtin_amdgcn_s_barrier();
            asm volatile("" ::: "memory");
        } else if (t == 14) {
            asm volatile("s_waitcnt vmcnt(0)" ::: "memory");  // B15 landed
            __builtin_amdgcn_s_barrier();
            asm volatile("" ::: "memory");
        }
    }

    // v = ln2*Σm + Σe + diag
    float v = fmaf(LN2, sm[0] + sm[1], se[0] + se[1] + ld);

    // wave reduce then block reduce
#pragma unroll
    for (int off = 32; off; off >>= 1)
        v += __shfl_down(v, off);
    if (lane == 0) wsum[wid] = v;
    __syncthreads();
    if (tid == 0) {
        float t = wsum[0] + wsum[1] + wsum[2] + wsum[3];
        atomicAdd(out, t * (1.0f / ((float)Nn * (float)Nn)));
    }
#undef STAGE_B
}

extern "C" void kernel_launch(void* const* d_in, const int* in_sizes, int n_in,
                              void* d_out, int out_size, void* d_ws, size_t ws_size,
                              hipStream_t stream) {
    const float* za   = (const float*)d_in[0];
    const float* zb   = (const float*)d_in[1];
    const float* bias = (const float*)d_in[2];

    unsigned char* wa = (unsigned char*)d_ws;
    unsigned char* wb = wa + (size_t)Nn * Dd;

    // zero the output accumulator (harness does not re-poison between replays)
    hipMemsetAsync(d_out, 0, sizeof(float), stream);

    // fp32 -> fp8 pre-pass (A pre-scaled by log2e)
    cvt_kernel<<<dim3(Nn * Dd / 2048), 256, 0, stream>>>(
        (const float4*)za, (const float4*)zb, (int2*)wa, (int2*)wb);

    // fused GEMM + loss: 128 M-tiles x 16 N-supertiles = 2048 blocks, 256 thr
    siglip_kernel<<<dim3(2048), 256, 0, stream>>>(wa, wb, bias, (float*)d_out);
}

// Round 26
// 116.680 us; speedup vs baseline: 6.7863x; 1.0454x over previous
//
#include <hip/hip_runtime.h>
#include <hip/hip_bf16.h>

#define Nn 16384
#define Dd 256
#define L2E 1.4426950408889634f
#define LN2 0.6931471805599453f

typedef __attribute__((ext_vector_type(8))) int int8v;
typedef __attribute__((ext_vector_type(16))) float f32x16;
typedef __attribute__((ext_vector_type(2))) float f32x2;

__device__ inline void gload_lds16(const void* g, void* l) {
    __builtin_amdgcn_global_load_lds(
        (const __attribute__((address_space(1))) void*)g,
        (__attribute__((address_space(3))) void*)l, 16, 0, 0);
}

// fp32 -> fp8 e4m3 (HW RNE). A pre-scaled by log2e: epilogue softplus works in
// exp2/log2 domain with no per-element muls.
__global__ __launch_bounds__(256) void cvt_kernel(
        const float4* __restrict__ a, const float4* __restrict__ b,
        int2* __restrict__ oa, int2* __restrict__ ob) {
    int i = blockIdx.x * 256 + threadIdx.x;
    float4 a0 = a[2 * i], a1 = a[2 * i + 1];
    float4 b0 = b[2 * i], b1 = b[2 * i + 1];
    int alo = __builtin_amdgcn_cvt_pk_fp8_f32(a0.x * L2E, a0.y * L2E, 0, false);
    alo     = __builtin_amdgcn_cvt_pk_fp8_f32(a0.z * L2E, a0.w * L2E, alo, true);
    int ahi = __builtin_amdgcn_cvt_pk_fp8_f32(a1.x * L2E, a1.y * L2E, 0, false);
    ahi     = __builtin_amdgcn_cvt_pk_fp8_f32(a1.z * L2E, a1.w * L2E, ahi, true);
    int blo = __builtin_amdgcn_cvt_pk_fp8_f32(b0.x, b0.y, 0, false);
    blo     = __builtin_amdgcn_cvt_pk_fp8_f32(b0.z, b0.w, blo, true);
    int bhi = __builtin_amdgcn_cvt_pk_fp8_f32(b1.x, b1.y, 0, false);
    bhi     = __builtin_amdgcn_cvt_pk_fp8_f32(b1.z, b1.w, bhi, true);
    oa[i] = make_int2(alo, ahi);
    ob[i] = make_int2(blo, bhi);
}

// ds_read_b128 pair from PRECOMPUTED byte offsets (XOR-deswizzle baked in at
// offset-precompute time; buffer base folds into the instruction immediate).
__device__ inline int8v rdoff(const unsigned char* base, int olo, int ohi) {
    int4 lo = *(const int4*)&base[olo];
    int4 hi = *(const int4*)&base[ohi];
    int8v r;
    r[0] = lo.x; r[1] = lo.y; r[2] = lo.z; r[3] = lo.w;
    r[4] = hi.x; r[5] = hi.y; r[6] = hi.z; r[7] = hi.w;
    return r;
}

#define MFMA_(A, B, C) __builtin_amdgcn_mfma_scale_f32_32x32x64_f8f6f4(       \
    (A), (B), (C), 0, 0, 0, 0x7F7F7F7F, 0, 0x7F7F7F7F)

// Fused MX-fp8 GEMM (sim' = log2e * za.zb^T, unit e8m0 scales) + siglip loss.
// R26 = R25 (2-blocks/CU persistent-A pipelined-B; VALU-bound at 40.6% busy
// vs 23.8% MfmaUtil) + ADDRESS HOISTING: ~29us of the 48us VALU time was
// per-panel recompute of LDS-read addresses (XOR swizzle math) + 64-bit
// staging addresses. (1) all 24 LDS byte-offsets precomputed into VGPRs
// once; (2) t-loop manually unrolled x2 so Bs0/Bs1 are static (base folds
// into ds_read immediate, no pointer select); (3) staging via 4 running
// pointers += 16384/panel. One acc generation (spill law), bias_acc
// C-operand, packed epilogue unchanged.
__global__ __launch_bounds__(256, 2) void siglip_kernel(
        const unsigned char* __restrict__ ga,   // za*log2e fp8 [16384][256]
        const unsigned char* __restrict__ gb,   // zb fp8 [16384][256]
        const float* __restrict__ bp,           // bias scalar
        float* __restrict__ out) {
    __shared__ unsigned char As[128 * 256];   // 32 KB, full-K A tile
    __shared__ unsigned char Bs0[64 * 256];   // 16 KB, B panel buffer 0
    __shared__ unsigned char Bs1[64 * 256];   // 16 KB, B panel buffer 1
    __shared__ float wsum[4];

    const int tid  = threadIdx.x;
    const int lane = tid & 63;
    const int wid  = tid >> 6;     // 0..3
    const int wm   = wid >> 1;     // 0..1 -> 64-row slice of the 128-row tile
    const int wn   = wid & 1;      // 0..1 -> 32-col slice of the 64-col panel
    const int l31  = lane & 31;
    const int h    = lane >> 5;

    // XCD-chunked bijective swizzle (grid 2048 = 8 XCD x 256); consecutive
    // nid share the A panel (same by) and sweep B -> per-XCD L2 locality.
    const int bid = blockIdx.x;
    const int nid = (bid & 7) * 256 + (bid >> 3);
    const int by  = nid >> 4;      // 0..127  M-tile (128 rows)
    const int bxs = nid & 15;      // 0..15   N-supertile (1024 cols)
    const size_t rowA0 = (size_t)by * 128;
    const int    rB0   = bxs * 1024;

    const float b2 = bp[0] * L2E;
    const int diagblk = (bxs == (by >> 3));
    const int dby7    = by & 7;    // which panel-pair holds this block's diag

    // ---- stage A once: 8 loads/thread; LDS dest linear, source swizzled ----
#pragma unroll
    for (int p = 0; p < 8; ++p) {
        int c = p * 256 + tid; int row = c >> 4;
        int scl = (c & 15) ^ (row & 15);
        gload_lds16(&ga[(rowA0 + row) * Dd + scl * 16], &As[c * 16]);
    }

    // ---- B staging: 4 running source pointers, advanced 16384 B per panel ----
    const unsigned char* gp[4];
#pragma unroll
    for (int p = 0; p < 4; ++p) {
        int c = p * 256 + tid; int row = c >> 4;
        int scl = (c & 15) ^ (row & 15);
        gp[p] = &gb[(size_t)(rB0 + row) * 256 + scl * 16];
    }
#define STAGE_ADV(BBUF)                                                       \
    {                                                                         \
        _Pragma("unroll")                                                     \
        for (int p = 0; p < 4; ++p) {                                         \
            gload_lds16(gp[p], &(BBUF)[(p * 256 + tid) * 16]);                \
            gp[p] += 16384;                                                   \
        }                                                                     \
    }
    STAGE_ADV(Bs0)   // panel 0
    STAGE_ADV(Bs1)   // panel 1

    // ---- precompute ALL LDS read offsets (XOR-deswizzle baked in) ----
    int offA[16], offB[8];
#pragma unroll
    for (int s = 0; s < 4; ++s) {
        int cb = s * 4 + h * 2;
#pragma unroll
        for (int mf = 0; mf < 2; ++mf) {
            int rr = wm * 64 + mf * 32 + l31;
            int x  = rr & 15;
            offA[s * 4 + mf * 2 + 0] = rr * 256 + ((cb) ^ x) * 16;
            offA[s * 4 + mf * 2 + 1] = rr * 256 + ((cb + 1) ^ x) * 16;
        }
        int rb = wn * 32 + l31;
        int xb = rb & 15;
        offB[s * 2 + 0] = rb * 256 + ((cb) ^ xb) * 16;
        offB[s * 2 + 1] = rb * 256 + ((cb + 1) ^ xb) * 16;
    }

    // read-only bias accumulator: C operand of every panel's first MFMA.
    f32x16 bias_acc;
#pragma unroll
    for (int q = 0; q < 16; ++q) bias_acc[q] = -b2;

    // outstanding: A(8)+B0(4)+B1(4)=16; wait to <=4 -> A and B0 landed.
    asm volatile("s_waitcnt vmcnt(4)" ::: "memory");
    __builtin_amdgcn_s_barrier();
    asm volatile("" ::: "memory");

    f32x2 sm = {0.f, 0.f}, se = {0.f, 0.f};
    float ld = 0.f;

    // ---- one panel: compute (zero addr VALU) -> barrier -> stage ->
    //      packed epilogue (overlaps stage flight) ----
#define PANEL(BBUF, T, DO_STAGE)                                              \
    {                                                                         \
        f32x16 acc[2];                                                        \
        {                                                                     \
            int8v aF0 = rdoff(As, offA[0], offA[1]);                          \
            int8v aF1 = rdoff(As, offA[2], offA[3]);                          \
            int8v bF  = rdoff(BBUF, offB[0], offB[1]);                        \
            acc[0] = MFMA_(aF0, bF, bias_acc);                                \
            acc[1] = MFMA_(aF1, bF, bias_acc);                                \
        }                                                                     \
        _Pragma("unroll")                                                     \
        for (int s = 1; s < 4; ++s) {                                         \
            int8v aF0 = rdoff(As, offA[s * 4 + 0], offA[s * 4 + 1]);          \
            int8v aF1 = rdoff(As, offA[s * 4 + 2], offA[s * 4 + 3]);          \
            int8v bF  = rdoff(BBUF, offB[s * 2 + 0], offB[s * 2 + 1]);        \
            acc[0] = MFMA_(aF0, bF, acc[0]);                                  \
            acc[1] = MFMA_(aF1, bF, acc[1]);                                  \
        }                                                                     \
        asm volatile("" ::: "memory");                                        \
        __builtin_amdgcn_s_barrier();                                         \
        asm volatile("" ::: "memory");                                        \
        if (DO_STAGE) STAGE_ADV(BBUF)                                         \
        _Pragma("unroll")                                                     \
        for (int mf = 0; mf < 2; ++mf)                                        \
            _Pragma("unroll")                                                 \
            for (int q = 0; q < 16; q += 2) {                                 \
                f32x2 yv = {acc[mf][q], acc[mf][q + 1]};                      \
                f32x2 mv = {fmaxf(yv[0], 0.f), fmaxf(yv[1], 0.f)};            \
                sm += mv;                                                     \
                f32x2 ev = {__builtin_amdgcn_exp2f(-fabsf(yv[0])),            \
                            __builtin_amdgcn_exp2f(-fabsf(yv[1]))};           \
                se += ev;                                                     \
            }                                                                 \
        if (diagblk && ((T) >> 1) == dby7 && wm == ((T) & 1)) {               \
            const int mfd = wn;                                               \
            _Pragma("unroll")                                                 \
            for (int q = 0; q < 16; ++q) {                                    \
                int rq = (q & 3) + 8 * (q >> 2) + 4 * h;                      \
                if (rq == l31) {                                              \
                    float y  = acc[mfd][q];                                   \
                    float u  = -(y + 2.f * b2);                               \
                    float ey = __builtin_amdgcn_exp2f(-fabsf(y));             \
                    float eu = __builtin_amdgcn_exp2f(-fabsf(u));             \
                    ld += (LN2 * fmaxf(u, 0.f) + eu) -                        \
                          (LN2 * fmaxf(y, 0.f) + ey);                         \
                }                                                             \
            }                                                                 \
        }                                                                     \
    }

#define WAIT4  asm volatile("s_waitcnt vmcnt(4)" ::: "memory");               \
               __builtin_amdgcn_s_barrier(); asm volatile("" ::: "memory");
#define WAIT0  asm volatile("s_waitcnt vmcnt(0)" ::: "memory");               \
               __builtin_amdgcn_s_barrier(); asm volatile("" ::: "memory");

    // ---- panels 0..13 (2x unrolled: static buffers), tail 14/15 ----
#pragma unroll 1
    for (int tt = 0; tt < 7; ++tt) {
        PANEL(Bs0, tt * 2, 1)
        WAIT4
        PANEL(Bs1, tt * 2 + 1, 1)
        WAIT4
    }
    PANEL(Bs0, 14, 0)
    WAIT0
    PANEL(Bs1, 15, 0)

    // v = ln2*Σm + Σe + diag
    float v = fmaf(LN2, sm[0] + sm[1], se[0] + se[1] + ld);

    // wave reduce then block reduce
#pragma unroll
    for (int off = 32; off; off >>= 1)
        v += __shfl_down(v, off);
    if (lane == 0) wsum[wid] = v;
    __syncthreads();
    if (tid == 0) {
        float t = wsum[0] + wsum[1] + wsum[2] + wsum[3];
        atomicAdd(out, t * (1.0f / ((float)Nn * (float)Nn)));
    }
#undef STAGE_ADV
#undef PANEL
#undef WAIT4
#undef WAIT0
}

extern "C" void kernel_launch(void* const* d_in, const int* in_sizes, int n_in,
                              void* d_out, int out_size, void* d_ws, size_t ws_size,
                              hipStream_t stream) {
    const float* za   = (const float*)d_in[0];
    const float* zb   = (const float*)d_in[1];
    const float* bias = (const float*)d_in[2];

    unsigned char* wa = (unsigned char*)d_ws;
    unsigned char* wb = wa + (size_t)Nn * Dd;

    // zero the output accumulator (harness does not re-poison between replays)
    hipMemsetAsync(d_out, 0, sizeof(float), stream);

    // fp32 -> fp8 pre-pass (A pre-scaled by log2e)
    cvt_kernel<<<dim3(Nn * Dd / 2048), 256, 0, stream>>>(
        (const float4*)za, (const float4*)zb, (int2*)wa, (int2*)wb);

    // fused GEMM + loss: 128 M-tiles x 16 N-supertiles = 2048 blocks, 256 thr
    siglip_kernel<<<dim3(2048), 256, 0, stream>>>(wa, wb, bias, (float*)d_out);
}